// Round 9
// baseline (437.871 us; speedup 1.0000x reference)
//
#include <hip/hip_runtime.h>
#include <hip/hip_bf16.h>
#include <string.h>

// CrossOp via bf16 MFMA (32x32x16) implicit-GEMM.
// Block = (b, h): one output row, 128 px, all 64 co. Grid 512, 8 waves (512 thr).
// Wave w: co-half (w&1)*32, px-group (w>>1)*32. 9 MFMA k-steps (K=144).
// 2-deep load pipeline: iteration s issues y(s+2) loads into one sr set and
// ds_writes the OTHER set (y(s+1), loaded last iteration) -> vmcnt wait has a
// full iteration of slack instead of one MFMA phase. Even/odd unroll keeps
// sr indexing static. Stores issued last + lgkmcnt-only barrier.
// LDS: [3 rows][130 cols][16 ci pad->24] bf16, double-buffered (37.4 KB).

typedef __attribute__((ext_vector_type(8))) short short8;
typedef __attribute__((ext_vector_type(16))) float f32x16;
typedef __attribute__((ext_vector_type(2))) unsigned int u32x2;
typedef __attribute__((ext_vector_type(4))) unsigned int u32x4;

#define NEG_SLOPE 0.01f

constexpr int CIP   = 24;              // shorts per (row,col) ci slab (48 B)
constexpr int COLS  = 130;             // 128 + 2 halo
constexpr int ROWP  = COLS * CIP;      // 3120 shorts
constexpr int BUFSH = 3 * ROWP;        // 9360 shorts = 18.7 KB per buffer

__device__ __forceinline__ short to_bf16s(float f) {
    unsigned u = __builtin_bit_cast(unsigned, f);
    u += 0x7fffu + ((u >> 16) & 1u);   // RNE
    return (short)(u >> 16);
}

__device__ __forceinline__ unsigned pack2(float a, float b) {
    __hip_bfloat162 t = __float22bfloat162_rn(float2{a, b});   // v_cvt_pk_bf16_f32
    unsigned u;
    memcpy(&u, &t, sizeof(u));
    return u;
}

__global__ __launch_bounds__(512, 4)
void crossop_mfma32(const float* __restrict__ xp, const float* __restrict__ yp,
                    const float* __restrict__ wp, const float* __restrict__ bp,
                    float* __restrict__ out)
{
    __shared__ __align__(16) short st[2][BUFSH];

    const int bid     = blockIdx.x;                     // 0..511
    const int logical = ((bid & 7) << 6) | (bid >> 3);  // XCD-chunked swizzle
    const int b       = logical >> 7;
    const int h       = logical & 127;

    const int tid  = threadIdx.x;
    const int lane = tid & 63;
    const int wid  = tid >> 6;             // 0..7
    const int l31  = lane & 31;
    const int hi   = lane >> 5;            // k-half / +4 co rows
    const int co0w = (wid & 1) << 5;       // wave's co base (0 or 32)
    const int pxg  = wid >> 1;             // wave's px-group (0..3)

    float* ntgt  = out;
    float* inter = out + (size_t)4 * 64 * 16384;
    const float* ybase = yp + (size_t)b * 32 * 16 * 16384;

    // ---------------- zero LDS once (halo cols 0,129 + OOB rows stay 0) ---
    {
        u32x4 zz = {0, 0, 0, 0};
        u32x4* z = (u32x4*)&st[0][0];
        for (int i = tid; i < (2 * BUFSH * 2) / 16; i += 512) z[i] = zz;
    }

    // ---------------- staging mapping: 512 threads, 12 values each --------
    const int ch = tid >> 7;               // ci quarter (0..3) -> ci 4*ch..4*ch+3
    const int wv = tid & 127;              // input col w = wv, LDS col wv+1
    float srA[3][4], srB[3][4];

#define STAGE_ISSUE(SR, SRC) do {                                             \
    const float* _s = (SRC);                                                  \
    _Pragma("unroll")                                                         \
    for (int it = 0; it < 3; ++it) {                                          \
        int hh = h + it - 1;                                                  \
        bool v = (unsigned)hh < 128u;                                         \
        const float* p = _s + (ptrdiff_t)(ch * 4) * 16384                     \
                            + (ptrdiff_t)hh * 128 + wv;                       \
        _Pragma("unroll")                                                     \
        for (int c = 0; c < 4; ++c)                                           \
            SR[it][c] = v ? p[(ptrdiff_t)c * 16384] : 0.f;                    \
    } } while (0)

#define STAGE_WRITE(SR, BUF) do {                                             \
    _Pragma("unroll")                                                         \
    for (int it = 0; it < 3; ++it) {                                          \
        if ((unsigned)(h + it - 1) < 128u) {                                  \
            u32x2 vv;                                                         \
            vv[0] = pack2(SR[it][0], SR[it][1]);                              \
            vv[1] = pack2(SR[it][2], SR[it][3]);                              \
            *(u32x2*)&(BUF)[it * ROWP + (wv + 1) * CIP + ch * 4] = vv;        \
        }                                                                     \
    } } while (0)

    // ---------------- persistent wy fragments (9 x short8 = 36 VGPR) ------
    short8 wy[9];
    #pragma unroll
    for (int sh = 0; sh < 9; ++sh) {
        #pragma unroll
        for (int j = 0; j < 8; ++j) {
            int ci = hi * 8 + j;           // k = (lane>>5)*8 + j within k-step
            wy[sh][j] = to_bf16s(wp[((co0w + l31) * 32 + 16 + ci) * 9 + sh]);
        }
    }

    // per-lane B column base (shorts) for this wave's px group
    const int cb = (pxg * 32 + l31) * CIP + hi * 8;

    // ---------------- prologue: x -> buf0; ox = conv_x + bias -------------
    STAGE_ISSUE(srA, xp + (size_t)b * 16 * 16384);
    STAGE_WRITE(srA, st[0]);
    __syncthreads();

    f32x16 ox;
    #pragma unroll
    for (int r = 0; r < 16; ++r)
        ox[r] = bp[co0w + (r & 3) + 8 * (r >> 2) + 4 * hi];
    {
        const short* sb = st[0];
        #pragma unroll
        for (int sh = 0; sh < 9; ++sh) {
            short8 ax;
            #pragma unroll
            for (int j = 0; j < 8; ++j) {
                int ci = hi * 8 + j;
                ax[j] = to_bf16s(wp[((co0w + l31) * 32 + ci) * 9 + sh]);
            }
            const int off = (sh / 3) * ROWP + (sh % 3) * CIP;
            ox = __builtin_amdgcn_mfma_f32_32x32x16_bf16(ax, *(const short8*)&sb[cb + off], ox, 0, 0, 0);
        }
    }

    // y0 -> buf1 (full-latency write, prologue only), then issue y1 -> srB
    STAGE_ISSUE(srA, ybase + (size_t)0 * 16 * 16384);
    STAGE_WRITE(srA, st[1]);
    STAGE_ISSUE(srB, ybase + (size_t)1 * 16 * 16384);
    __syncthreads();

    // ---------------- s-loop, 2-deep pipeline, even/odd unroll -------------
    f32x16 ms;
    #pragma unroll
    for (int r = 0; r < 16; ++r) ms[r] = 0.f;

#define BODY(S, SRN, SRO) do {                                                \
    const short* sb = st[((S) + 1) & 1];                                      \
    if ((S) + 2 < 32) STAGE_ISSUE(SRN, ybase + (size_t)((S) + 2) * 16 * 16384); \
    f32x16 acc = ox;                                                          \
    _Pragma("unroll")                                                         \
    for (int sh = 0; sh < 9; ++sh) {                                          \
        const int off = (sh / 3) * ROWP + (sh % 3) * CIP;                     \
        acc = __builtin_amdgcn_mfma_f32_32x32x16_bf16(                        \
            wy[sh], *(const short8*)&sb[cb + off], acc, 0, 0, 0);             \
    }                                                                         \
    if ((S) + 1 < 32) STAGE_WRITE(SRO, st[(S) & 1]);                          \
    {                                                                         \
        float* p0 = inter + ((size_t)(b * 32 + (S)) * 64 + co0w + 4 * hi) * 16384 \
                  + (size_t)h * 128 + pxg * 32 + l31;                         \
        _Pragma("unroll")                                                     \
        for (int r = 0; r < 16; ++r) {                                        \
            float v = acc[r];                                                 \
            v = v >= 0.f ? v : NEG_SLOPE * v;                                 \
            __builtin_nontemporal_store(v, p0 + (ptrdiff_t)((r & 3) + 8 * (r >> 2)) * 16384); \
            ms[r] += v;                                                       \
        }                                                                     \
    }                                                                         \
    asm volatile("s_waitcnt lgkmcnt(0)" ::: "memory");                        \
    __builtin_amdgcn_s_barrier();                                             \
    asm volatile("" ::: "memory");                                            \
} while (0)

    for (int s = 0; s < 32; s += 2) {
        BODY(s,     srA, srB);   // issue y(s+2) into A; write B (= y(s+1))
        BODY(s + 1, srB, srA);   // issue y(s+3) into B; write A (= y(s+2))
    }

    // ---------------- mean over Sy ----------------------------------------
    {
        float* p0 = ntgt + ((size_t)b * 64 + co0w + 4 * hi) * 16384
                  + (size_t)h * 128 + pxg * 32 + l31;
        #pragma unroll
        for (int r = 0; r < 16; ++r)
            __builtin_nontemporal_store(ms[r] * 0.03125f,
                                        p0 + (ptrdiff_t)((r & 3) + 8 * (r >> 2)) * 16384);
    }
#undef BODY
#undef STAGE_ISSUE
#undef STAGE_WRITE
}

extern "C" void kernel_launch(void* const* d_in, const int* in_sizes, int n_in,
                              void* d_out, int out_size, void* d_ws, size_t ws_size,
                              hipStream_t stream) {
    const float* x    = (const float*)d_in[0];
    const float* y    = (const float*)d_in[1];
    const float* wgt  = (const float*)d_in[2];
    const float* bias = (const float*)d_in[3];
    float* out = (float*)d_out;

    crossop_mfma32<<<512, 512, 0, stream>>>(x, y, wgt, bias, out);
}

// Round 10
// 146.437 us; speedup vs baseline: 2.9902x; 2.9902x over previous
//
#include <hip/hip_runtime.h>
#include <hip/hip_bf16.h>
#include <string.h>

// CrossOp via bf16 MFMA (32x32x16) implicit-GEMM.
// Block = (b, h): one output row, 128 px, all 64 co. Grid 512, 8 waves (512 thr).
// Wave w: co-half (w&1)*32, px-group (w>>1)*32. 9 MFMA k-steps (K=144).
// 2-deep load pipeline with ONE register set (write-then-reissue):
//   iter s: ds_write sr (=y(s+1), loaded iter s-1)  <- vmcnt(16): skips stores
//           reissue sr <- y(s+2) global loads
//           MFMA on st[(s+1)&1] (=y_s); leaky+NT stores; lgkm-only barrier.
// Stores are never drained in the loop (counted vmcnt leaves them in flight).
// LDS: [3 rows][130 cols][16 ci pad->24] bf16, double-buffered (37.4 KB).

typedef __attribute__((ext_vector_type(8))) short short8;
typedef __attribute__((ext_vector_type(16))) float f32x16;
typedef __attribute__((ext_vector_type(2))) unsigned int u32x2;
typedef __attribute__((ext_vector_type(4))) unsigned int u32x4;

#define NEG_SLOPE 0.01f

constexpr int CIP   = 24;              // shorts per (row,col) ci slab (48 B)
constexpr int COLS  = 130;             // 128 + 2 halo
constexpr int ROWP  = COLS * CIP;      // 3120 shorts
constexpr int BUFSH = 3 * ROWP;        // 9360 shorts = 18.7 KB per buffer

__device__ __forceinline__ short to_bf16s(float f) {
    unsigned u = __builtin_bit_cast(unsigned, f);
    u += 0x7fffu + ((u >> 16) & 1u);   // RNE
    return (short)(u >> 16);
}

__device__ __forceinline__ unsigned pack2(float a, float b) {
    __hip_bfloat162 t = __float22bfloat162_rn(float2{a, b});   // v_cvt_pk_bf16_f32
    unsigned u;
    memcpy(&u, &t, sizeof(u));
    return u;
}

__global__ __launch_bounds__(512, 4)
void crossop_mfma32(const float* __restrict__ xp, const float* __restrict__ yp,
                    const float* __restrict__ wp, const float* __restrict__ bp,
                    float* __restrict__ out)
{
    __shared__ __align__(16) short st[2][BUFSH];

    const int bid     = blockIdx.x;                     // 0..511
    const int logical = ((bid & 7) << 6) | (bid >> 3);  // XCD-chunked swizzle
    const int b       = logical >> 7;
    const int h       = logical & 127;

    const int tid  = threadIdx.x;
    const int lane = tid & 63;
    const int wid  = tid >> 6;             // 0..7
    const int l31  = lane & 31;
    const int hi   = lane >> 5;            // k-half / +4 co rows
    const int co0w = (wid & 1) << 5;       // wave's co base (0 or 32)
    const int pxg  = wid >> 1;             // wave's px-group (0..3)

    float* ntgt  = out;
    float* inter = out + (size_t)4 * 64 * 16384;
    const float* ybase = yp + (size_t)b * 32 * 16 * 16384;

    // ---------------- zero LDS once (halo cols 0,129 + OOB rows stay 0) ---
    {
        u32x4 zz = {0, 0, 0, 0};
        u32x4* z = (u32x4*)&st[0][0];
        for (int i = tid; i < (2 * BUFSH * 2) / 16; i += 512) z[i] = zz;
    }

    // ---------------- staging mapping: 512 threads, 12 values each --------
    const int ch = tid >> 7;               // ci quarter (0..3) -> ci 4*ch..4*ch+3
    const int wv = tid & 127;              // input col w = wv, LDS col wv+1
    float sr[3][4];

#define STAGE_ISSUE(SRC) do {                                                 \
    const float* _s = (SRC);                                                  \
    _Pragma("unroll")                                                         \
    for (int it = 0; it < 3; ++it) {                                          \
        int hh = h + it - 1;                                                  \
        bool v = (unsigned)hh < 128u;                                         \
        const float* p = _s + (ptrdiff_t)(ch * 4) * 16384                     \
                            + (ptrdiff_t)hh * 128 + wv;                       \
        _Pragma("unroll")                                                     \
        for (int c = 0; c < 4; ++c)                                           \
            sr[it][c] = v ? p[(ptrdiff_t)c * 16384] : 0.f;                    \
    } } while (0)

#define STAGE_WRITE(BUF) do {                                                 \
    _Pragma("unroll")                                                         \
    for (int it = 0; it < 3; ++it) {                                          \
        if ((unsigned)(h + it - 1) < 128u) {                                  \
            u32x2 vv;                                                         \
            vv[0] = pack2(sr[it][0], sr[it][1]);                              \
            vv[1] = pack2(sr[it][2], sr[it][3]);                              \
            *(u32x2*)&(BUF)[it * ROWP + (wv + 1) * CIP + ch * 4] = vv;        \
        }                                                                     \
    } } while (0)

    // ---------------- persistent wy fragments (9 x short8 = 36 VGPR) ------
    short8 wy[9];
    #pragma unroll
    for (int sh = 0; sh < 9; ++sh) {
        #pragma unroll
        for (int j = 0; j < 8; ++j) {
            int ci = hi * 8 + j;           // k = (lane>>5)*8 + j within k-step
            wy[sh][j] = to_bf16s(wp[((co0w + l31) * 32 + 16 + ci) * 9 + sh]);
        }
    }

    // per-lane B column base (shorts) for this wave's px group
    const int cb = (pxg * 32 + l31) * CIP + hi * 8;

    // ---------------- prologue: x -> buf0; ox = conv_x + bias -------------
    STAGE_ISSUE(xp + (size_t)b * 16 * 16384);
    STAGE_WRITE(st[0]);
    __syncthreads();

    f32x16 ox;
    #pragma unroll
    for (int r = 0; r < 16; ++r)
        ox[r] = bp[co0w + (r & 3) + 8 * (r >> 2) + 4 * hi];
    {
        const short* sb = st[0];
        #pragma unroll
        for (int sh = 0; sh < 9; ++sh) {
            short8 ax;
            #pragma unroll
            for (int j = 0; j < 8; ++j) {
                int ci = hi * 8 + j;
                ax[j] = to_bf16s(wp[((co0w + l31) * 32 + ci) * 9 + sh]);
            }
            const int off = (sh / 3) * ROWP + (sh % 3) * CIP;
            ox = __builtin_amdgcn_mfma_f32_32x32x16_bf16(ax, *(const short8*)&sb[cb + off], ox, 0, 0, 0);
        }
    }

    // y0 -> buf1 (full-latency write, prologue only), then prefetch y1 -> sr
    STAGE_ISSUE(ybase + (size_t)0 * 16 * 16384);
    STAGE_WRITE(st[1]);
    STAGE_ISSUE(ybase + (size_t)1 * 16 * 16384);
    __syncthreads();

    // ---------------- s-loop: write-then-reissue 2-deep pipeline -----------
    f32x16 ms;
    #pragma unroll
    for (int r = 0; r < 16; ++r) ms[r] = 0.f;

    for (int s = 0; s < 32; ++s) {
        // 1) ds_write sr (= y(s+1), loaded last iteration). The vmcnt wait
        //    here is counted (loads preceded last iter's stores in issue
        //    order) -> stores stay in flight.
        if (s + 1 < 32) STAGE_WRITE(st[s & 1]);

        // 2) reissue the SAME sr registers with y(s+2) loads
        if (s + 2 < 32) STAGE_ISSUE(ybase + (size_t)(s + 2) * 16 * 16384);

        // 3) MFMA phase on y_s (st[(s+1)&1])
        const short* sb = st[(s + 1) & 1];
        f32x16 acc = ox;
        #pragma unroll
        for (int sh = 0; sh < 9; ++sh) {
            const int off = (sh / 3) * ROWP + (sh % 3) * CIP;
            acc = __builtin_amdgcn_mfma_f32_32x32x16_bf16(wy[sh], *(const short8*)&sb[cb + off], acc, 0, 0, 0);
        }

        // 4) leaky + NT stores issued LAST — never drained in the loop
        {
            float* p0 = inter + ((size_t)(b * 32 + s) * 64 + co0w + 4 * hi) * 16384
                      + (size_t)h * 128 + pxg * 32 + l31;
            #pragma unroll
            for (int r = 0; r < 16; ++r) {
                float v = acc[r];
                v = v >= 0.f ? v : NEG_SLOPE * v;
                __builtin_nontemporal_store(v, p0 + (ptrdiff_t)((r & 3) + 8 * (r >> 2)) * 16384);
                ms[r] += v;
            }
        }

        // 5) LDS-only barrier: wait ds ops, NOT the global stores
        asm volatile("s_waitcnt lgkmcnt(0)" ::: "memory");
        __builtin_amdgcn_s_barrier();
        asm volatile("" ::: "memory");
    }

    // ---------------- mean over Sy ----------------------------------------
    {
        float* p0 = ntgt + ((size_t)b * 64 + co0w + 4 * hi) * 16384
                  + (size_t)h * 128 + pxg * 32 + l31;
        #pragma unroll
        for (int r = 0; r < 16; ++r)
            __builtin_nontemporal_store(ms[r] * 0.03125f,
                                        p0 + (ptrdiff_t)((r & 3) + 8 * (r >> 2)) * 16384);
    }
#undef STAGE_ISSUE
#undef STAGE_WRITE
}

extern "C" void kernel_launch(void* const* d_in, const int* in_sizes, int n_in,
                              void* d_out, int out_size, void* d_ws, size_t ws_size,
                              hipStream_t stream) {
    const float* x    = (const float*)d_in[0];
    const float* y    = (const float*)d_in[1];
    const float* wgt  = (const float*)d_in[2];
    const float* bias = (const float*)d_in[3];
    float* out = (float*)d_out;

    crossop_mfma32<<<512, 512, 0, stream>>>(x, y, wgt, bias, out);
}